// Round 10
// baseline (119.579 us; speedup 1.0000x reference)
//
#include <hip/hip_runtime.h>
#include <hip/hip_fp16.h>

#define N_NODES 50000
#define N_EDGES 800000
#define D_FEAT  64
#define CAP     32                      // csr slots/node; deg>32 -> oflow (fp32)
#define NBUCK   196                     // dst buckets of 256 nodes
#define BIN_BLOCKS 256
#define SLICE_CAP 64                    // edges per (bucket,block) slice; lambda=20.9
#define SPB     256                     // per-block spill slots (slice overflow, ~never)
#define OFC     128                     // per-bucket LDS overflow list (deg>32 excess)

// ---------------------------------------------------------------------------
// Round 18: r17 structure with the instruction-count waste removed.
//   - bin edge phase: ONE iteration of int4/float4 quad loads (thread gq owns
//     edge-quad gq; 200000 quads exactly). Was ~3 serial iterations x 3
//     scalar loads each. Blocks 196-255 idle but publish zero headers.
//   - gather drain: uint4 loads = 2 entries per 16B load (was 8B scalar).
//   - gather pull phase / overflow / convert: byte-identical to passing r17.
// ---------------------------------------------------------------------------

typedef unsigned uvec4 __attribute__((ext_vector_type(4)));

__device__ __forceinline__ unsigned pack_entry(unsigned s, float w) {
    return (s << 16) | (unsigned)__half_as_ushort(__float2half(w));
}
__device__ __forceinline__ float entry_w(unsigned e) {
    return __half2float(__ushort_as_half((unsigned short)(e & 0xffffu)));
}
__device__ __forceinline__ float2 h2f2(unsigned u) {
    __half2 h = *reinterpret_cast<__half2*>(&u);
    return __half22float2(h);
}

// Pass 1: scatter edge quads into static (bucket,block) slices + fused convert.
__global__ void __launch_bounds__(1024)
bin_kernel(const int* __restrict__ src, const int* __restrict__ dst,
           const float* __restrict__ weight, const float* __restrict__ queue,
           uint2* __restrict__ ebuf, unsigned* __restrict__ hcnt,
           unsigned* __restrict__ scnt, uint2* __restrict__ spillbuf,
           __half* __restrict__ qh) {
    __shared__ unsigned lcur[NBUCK];
    __shared__ unsigned lsp;
    const int tid = threadIdx.x;
    const int bi  = blockIdx.x;
    if (tid < NBUCK) lcur[tid] = 0;
    if (tid == 0) lsp = 0;
    __syncthreads();

    const int gq = bi * 1024 + tid;               // quad index; 200000 total
    if (gq < N_EDGES / 4) {
        const int4   d4 = reinterpret_cast<const int4*>(dst)[gq];
        const int4   s4 = reinterpret_cast<const int4*>(src)[gq];
        const float4 w4 = reinterpret_cast<const float4*>(weight)[gq];
        const int   dd[4] = {d4.x, d4.y, d4.z, d4.w};
        const int   ss[4] = {s4.x, s4.y, s4.z, s4.w};
        const float ww[4] = {w4.x, w4.y, w4.z, w4.w};
#pragma unroll
        for (int j = 0; j < 4; ++j) {
            const unsigned b = (unsigned)dd[j] >> 8;
            const unsigned pos = atomicAdd(&lcur[b], 1u);
            if (pos < SLICE_CAP) {
                ebuf[(size_t)(b * 256 + bi) * SLICE_CAP + pos] =
                    make_uint2((unsigned)ss[j] | ((unsigned)(dd[j] & 255) << 16),
                               __float_as_uint(ww[j]));
            } else {                              // slice overflow (~14 sigma)
                const unsigned sp = atomicAdd(&lsp, 1u);
                if (sp < SPB)
                    spillbuf[bi * SPB + sp] =
                        make_uint2((unsigned)ss[j] | ((unsigned)dd[j] << 16),
                                   __float_as_uint(ww[j]));
            }
        }
    }
    __syncthreads();
    if (tid < NBUCK) hcnt[tid * 256 + bi] = lcur[tid];   // hcnt[b][bi]
    if (tid == 0) scnt[bi] = lsp;

    // Fused queue fp32 -> fp16 convert (~3 iterations, streaming).
    const int gid = bi * 1024 + tid;              // 262144 threads
    for (int t = gid; t < N_NODES * D_FEAT / 4; t += BIN_BLOCKS * 1024) {
        const float4 q = reinterpret_cast<const float4*>(queue)[t];
        ushort4 h;
        h.x = __half_as_ushort(__float2half(q.x));
        h.y = __half_as_ushort(__float2half(q.y));
        h.z = __half_as_ushort(__float2half(q.z));
        h.w = __half_as_ushort(__float2half(q.w));
        reinterpret_cast<ushort4*>(qh)[t] = h;
    }
}

// Pass 2 (fused csr+pull): one block per bucket; CSR built in LDS, pulled
// in place. Wave w handles nodes w*16..w*16+15 of the bucket.
__global__ void __launch_bounds__(1024)
gather_kernel(const uint2* __restrict__ ebuf, const unsigned* __restrict__ hcnt,
              const unsigned* __restrict__ scnt, const uint2* __restrict__ spillbuf,
              const __half* __restrict__ qh, const float* __restrict__ queue,
              float* __restrict__ out) {
    __shared__ unsigned lcnt[256];
    __shared__ unsigned csr_l[256 * CAP];         // 32 KB
    __shared__ uint2    oflow[OFC];               // deg>32 excess (fp32 path)
    __shared__ unsigned ocnt;
    const int b   = blockIdx.x;                   // bucket 0..195
    const int tid = threadIdx.x;
    if (tid < 256) lcnt[tid] = 0;
    if (tid == 0) ocnt = 0;
    __syncthreads();

    // Phase 1: drain the bucket's 256 slices into the LDS CSR.
    // 4 threads/slice; uint4 = 2 entries per load.
    {
        const int slice = tid >> 2, sub = tid & 3;
        const int hb = min((int)hcnt[b * 256 + slice], SLICE_CAP);
        const uint2* sl = ebuf + (size_t)(b * 256 + slice) * SLICE_CAP;
        for (int j = sub * 2; j < hb; j += 8) {   // ~3 iterations
            const uvec4 u2 = *reinterpret_cast<const uvec4*>(sl + j);
#pragma unroll
            for (int h = 0; h < 2; ++h) {
                if (j + h >= hb) break;
                const unsigned ex = h ? u2.z : u2.x;
                const unsigned ew = h ? u2.w : u2.y;
                const unsigned nlo = ex >> 16;
                const unsigned pos = atomicAdd(&lcnt[nlo], 1u);
                if (pos < CAP) {
                    csr_l[nlo * CAP + pos] =
                        pack_entry(ex & 0xffffu, __uint_as_float(ew));
                } else {                          // deg > 32: exact fp32 path
                    const unsigned o = atomicAdd(&ocnt, 1u);
                    if (o < OFC)
                        oflow[o] = make_uint2((ex & 0xffffu) |
                                              ((((unsigned)b << 8) + nlo) << 16), ew);
                }
            }
        }
    }
    // Phase 1.5: import global slice-overflow spills for this bucket (~none).
    if (tid < 256) {
        const int sc = min((int)scnt[tid], SPB);
        for (int j = 0; j < sc; ++j) {
            const uint2 u = spillbuf[tid * SPB + j];
            if ((u.x >> 16) >> 8 == (unsigned)b) {
                const unsigned o = atomicAdd(&ocnt, 1u);
                if (o < OFC) oflow[o] = u;
            }
        }
    }
    __syncthreads();

    // Phase 2: pull. 16 waves x 16 nodes.
    const int wv = tid >> 6, lane = tid & 63;
    const int g = lane >> 3;                      // edge group 0..7
    const int k = lane & 7;                       // 16B chunk within 128B row
    const unsigned oc = min(ocnt, (unsigned)OFC);

    for (int q = 0; q < 16; ++q) {
        const int nlo = wv * 16 + q;
        const unsigned node = ((unsigned)b << 8) + (unsigned)nlo;
        if (node >= N_NODES) break;               // bucket 195 tail only
        const int c = min((int)lcnt[nlo], CAP);

        float a0 = 0, a1 = 0, a2 = 0, a3 = 0, a4 = 0, a5 = 0, a6 = 0, a7 = 0;
#pragma unroll
        for (int it = 0; it < 4; ++it) {
            if (it * 8 < c) {                     // wave-uniform tier skip
                const int slot = g + it * 8;
                unsigned e = csr_l[nlo * CAP + slot];    // 8-lane broadcast
                if (slot >= c) e = 0u;            // masked: src=0, w=fp16(0)
                const float w = entry_w(e);
                const uvec4 r = *reinterpret_cast<const uvec4*>(
                    qh + (size_t)(e >> 16) * D_FEAT + k * 8);
                const float2 f0 = h2f2(r.x), f1 = h2f2(r.y),
                             f2 = h2f2(r.z), f3 = h2f2(r.w);
                a0 = fmaf(f0.x, w, a0);  a1 = fmaf(f0.y, w, a1);
                a2 = fmaf(f1.x, w, a2);  a3 = fmaf(f1.y, w, a3);
                a4 = fmaf(f2.x, w, a4);  a5 = fmaf(f2.y, w, a5);
                a6 = fmaf(f3.x, w, a6);  a7 = fmaf(f3.y, w, a7);
            }
        }
#pragma unroll
        for (int m = 8; m <= 32; m <<= 1) {       // cross-group reduce
            a0 += __shfl_xor(a0, m);  a1 += __shfl_xor(a1, m);
            a2 += __shfl_xor(a2, m);  a3 += __shfl_xor(a3, m);
            a4 += __shfl_xor(a4, m);  a5 += __shfl_xor(a5, m);
            a6 += __shfl_xor(a6, m);  a7 += __shfl_xor(a7, m);
        }
        if (oc > 0 && lane < 8) {                 // overflow edges (fp32, rare)
            for (unsigned o = 0; o < oc; ++o) {
                const uint2 u = oflow[o];
                if ((u.x >> 16) == node) {
                    const float w = __uint_as_float(u.y);
                    const float* qr = queue + (size_t)(u.x & 0xffffu) * D_FEAT + lane * 8;
                    a0 = fmaf(qr[0], w, a0);  a1 = fmaf(qr[1], w, a1);
                    a2 = fmaf(qr[2], w, a2);  a3 = fmaf(qr[3], w, a3);
                    a4 = fmaf(qr[4], w, a4);  a5 = fmaf(qr[5], w, a5);
                    a6 = fmaf(qr[6], w, a6);  a7 = fmaf(qr[7], w, a7);
                }
            }
        }
        if (lane < 8) {                           // 8 lanes x 32B = 256B row
            float* o = out + (size_t)node * D_FEAT + lane * 8;
            *reinterpret_cast<float4*>(o)     = make_float4(a0, a1, a2, a3);
            *reinterpret_cast<float4*>(o + 4) = make_float4(a4, a5, a6, a7);
        }
    }
}

// --- Fallback (round-1 scatter) if ws_size is ever too small ---------------
__global__ void __launch_bounds__(256)
scatter_add_kernel(const float* __restrict__ queue,
                   const float* __restrict__ weight,
                   const int* __restrict__ src,
                   const int* __restrict__ dst,
                   float* __restrict__ out) {
    long long tid = (long long)blockIdx.x * blockDim.x + threadIdx.x;
    int e = (int)(tid >> 4);
    int c = ((int)tid & 15) << 2;
    if (e >= N_EDGES) return;
    int s = src[e], d = dst[e];
    float w = weight[e];
    const float4 q = *reinterpret_cast<const float4*>(queue + (size_t)s * D_FEAT + c);
    float* o = out + (size_t)d * D_FEAT + c;
    atomicAdd(o + 0, q.x * w);
    atomicAdd(o + 1, q.y * w);
    atomicAdd(o + 2, q.z * w);
    atomicAdd(o + 3, q.w * w);
}

extern "C" void kernel_launch(void* const* d_in, const int* in_sizes, int n_in,
                              void* d_out, int out_size, void* d_ws, size_t ws_size,
                              hipStream_t stream) {
    const float* queue  = (const float*)d_in[0];
    const float* weight = (const float*)d_in[1];
    const int*   src    = (const int*)d_in[2];
    const int*   dst    = (const int*)d_in[3];
    float* out = (float*)d_out;

    // Workspace layout (16B-aligned blocks). Nothing needs pre-zeroing:
    //   qh:       N_NODES*D_FEAT __half          (6.4 MB)
    //   ebuf:     NBUCK*256*SLICE_CAP uint2      (25.7 MB)
    //   spillbuf: 256*SPB uint2                  (512 KB)
    //   hcnt:     NBUCK*256 unsigned             (written every call)
    //   scnt:     256 unsigned                   (written every call)
    const size_t qh_bytes    = (size_t)N_NODES * D_FEAT * sizeof(__half);
    const size_t ebuf_bytes  = (size_t)NBUCK * 256 * SLICE_CAP * sizeof(uint2);
    const size_t spill_bytes = (size_t)256 * SPB * sizeof(uint2);
    const size_t hcnt_bytes  = (size_t)NBUCK * 256 * sizeof(unsigned);
    const size_t need = qh_bytes + ebuf_bytes + spill_bytes + hcnt_bytes
                      + 256 * sizeof(unsigned);

    if (ws_size < need) {  // safety fallback: round-1 scatter path
        hipMemsetAsync(out, 0, (size_t)out_size * sizeof(float), stream);
        const long long total = (long long)N_EDGES * 16;
        scatter_add_kernel<<<(int)((total + 255) / 256), 256, 0, stream>>>(
            queue, weight, src, dst, out);
        return;
    }

    char* ws = (char*)d_ws;
    __half*   qh       = (__half*)ws;
    uint2*    ebuf     = (uint2*)(ws + qh_bytes);
    uint2*    spillbuf = (uint2*)(ws + qh_bytes + ebuf_bytes);
    unsigned* hcnt     = (unsigned*)(ws + qh_bytes + ebuf_bytes + spill_bytes);
    unsigned* scnt     = hcnt + NBUCK * 256;

    bin_kernel<<<BIN_BLOCKS, 1024, 0, stream>>>(
        src, dst, weight, queue, ebuf, hcnt, scnt, spillbuf, qh);
    gather_kernel<<<NBUCK, 1024, 0, stream>>>(
        ebuf, hcnt, scnt, spillbuf, qh, queue, out);
}